// Round 4
// baseline (70.981 us; speedup 1.0000x reference)
//
#include <hip/hip_runtime.h>
#include <hip/hip_bf16.h>

// B=128, D=64.
//   c_vec[b,c] = mean_{h,w} x[b,c,h,w]
//   h_vec[b,w] = mean_{c,h} x[b,c,h,w]
//   w_vec[b,h] = mean_{c,w} x[b,c,h,w]
//   f*[b,i,o] = sigmoid(sum_j W*[i,o,j] * vec[b,j])
//   LR[b,c,p,q] = sum_i fc[b,i,c]*fh[b,i,p]*fw[b,i,q]
// Stage 3 (c-sweep): per c, full 16KB [p][q] plane via
//   M[p,q] = sum_k (fc[k,c]*fh[k,p]) * fw[k,q]  -> MFMA(A=fw rows=q, B=A' cols=p),
// written contiguously so L2 evicts full 16KB spans (DRAM row-friendly).

#define NB 128

typedef __attribute__((ext_vector_type(8))) short bf16x8;
typedef __attribute__((ext_vector_type(4))) float f32x4;

__device__ __forceinline__ float bf2f(short s) {
    return __uint_as_float(((unsigned)(unsigned short)s) << 16);
}
__device__ __forceinline__ unsigned packbf2(float a, float b) {
    unsigned ua = __float_as_uint(a); ua += 0x7fffu + ((ua >> 16) & 1u);
    unsigned ub = __float_as_uint(b); ub += 0x7fffu + ((ub >> 16) & 1u);
    return (ua >> 16) | (ub & 0xffff0000u);
}
__device__ __forceinline__ unsigned short f2bf(float f) {
    unsigned u = __float_as_uint(f); u += 0x7fffu + ((u >> 16) & 1u);
    return (unsigned short)(u >> 16);
}

// ---------------------------------------------------------------------------
// Kernel 1: fused triple pooling. Grid 1024 = (b, cblk of 8 c).
// ---------------------------------------------------------------------------
__global__ __launch_bounds__(256) void pool_kernel(const float* __restrict__ x,
                                                   float* __restrict__ cvecT,    // [64][128]
                                                   float* __restrict__ hv_part,  // [8][64][128] per-w (ref h_vec)
                                                   float* __restrict__ wv_part)  // [8][64][128] per-h (ref w_vec)
{
    const int blk  = blockIdx.x;
    const int b    = blk >> 3;
    const int cblk = blk & 7;
    const int t    = threadIdx.x;
    const int wv   = t >> 6;
    const int l    = t & 63;
    const int lg   = l >> 4;
    const int lw   = l & 15;

    __shared__ float cpart[8][4];
    __shared__ float hsum_l[64];
    __shared__ float wpart[4][64];

    const float* xb = x + (size_t)b * 262144 + (size_t)cblk * 32768;

    float cs[8];
    float acc_h[4] = {0.f, 0.f, 0.f, 0.f};
    float acc_w[4] = {0.f, 0.f, 0.f, 0.f};

#pragma unroll
    for (int cc = 0; cc < 8; ++cc) {
        const float* xc = xb + cc * 4096 + wv * 1024 + 4 * l;
        float sc = 0.f;
#pragma unroll
        for (int k = 0; k < 4; ++k) {
            float4 v = *reinterpret_cast<const float4*>(xc + k * 256);
            float s = (v.x + v.y) + (v.z + v.w);
            sc += s;
            acc_h[k] += s;
            acc_w[0] += v.x; acc_w[1] += v.y; acc_w[2] += v.z; acc_w[3] += v.w;
        }
        cs[cc] = sc;
    }

#pragma unroll
    for (int cc = 0; cc < 8; ++cc) {
        float v = cs[cc];
#pragma unroll
        for (int off = 32; off >= 1; off >>= 1) v += __shfl_xor(v, off, 64);
        if (l == 0) cpart[cc][wv] = v;
    }
#pragma unroll
    for (int k = 0; k < 4; ++k) {
        float v = acc_h[k];
        v += __shfl_xor(v, 1, 64);
        v += __shfl_xor(v, 2, 64);
        v += __shfl_xor(v, 4, 64);
        v += __shfl_xor(v, 8, 64);
        if (lw == 0) hsum_l[wv * 16 + k * 4 + lg] = v;
    }
#pragma unroll
    for (int m = 0; m < 4; ++m) {
        float v = acc_w[m];
        v += __shfl_xor(v, 16, 64);
        v += __shfl_xor(v, 32, 64);
        if (lg == 0) wpart[wv][lw * 4 + m] = v;
    }
    __syncthreads();

    const float scale = 1.f / 4096.f;
    if (t < 8) {
        float s = cpart[t][0] + cpart[t][1] + cpart[t][2] + cpart[t][3];
        cvecT[(cblk * 8 + t) * NB + b] = s * scale;
    }
    if (t < 64) {
        wv_part[(cblk * 64 + t) * NB + b] = hsum_l[t] * scale;               // per-h
        float ws_ = wpart[0][t] + wpart[1][t] + wpart[2][t] + wpart[3][t];   // per-w
        hv_part[(cblk * 64 + t) * NB + b] = ws_ * scale;
    }
}

// ---------------------------------------------------------------------------
// Kernel 2: f*[b,i,o] = sigmoid(sum_j W[i,o,j]*vec[b,j]); writes TRANSPOSED
// bf16 fT[b][o][i]. Grid 192 = (branch, i). h/w branches sum 8 pool partials.
// ---------------------------------------------------------------------------
__global__ __launch_bounds__(256) void fvec_kernel(const float* __restrict__ Wc,
                                                   const float* __restrict__ Wh,
                                                   const float* __restrict__ Ww,
                                                   const float* __restrict__ cvecT,
                                                   const float* __restrict__ hv_part,
                                                   const float* __restrict__ wv_part,
                                                   unsigned short* __restrict__ fcT,
                                                   unsigned short* __restrict__ fhT,
                                                   unsigned short* __restrict__ fwT)
{
    const int br = blockIdx.x >> 6;
    const int i  = blockIdx.x & 63;
    const float* W = (br == 0) ? Wc : (br == 1) ? Wh : Ww;
    const float* V = (br == 0) ? cvecT : (br == 1) ? hv_part : wv_part;
    unsigned short* outT = (br == 0) ? fcT : (br == 1) ? fhT : fwT;

    __shared__ float Wt[64][64];     // Wt[j][o]
    __shared__ float vl[64 * NB];    // vl[j][b]

    const int t = threadIdx.x;
    {
        const float* Wi = W + (size_t)i * 4096;
#pragma unroll
        for (int r = 0; r < 4; ++r) {
            int f = t + 256 * r;
            float4 v = reinterpret_cast<const float4*>(Wi)[f];
            int o = (4 * f) >> 6;
            int j = (4 * f) & 63;
            Wt[j + 0][o] = v.x; Wt[j + 1][o] = v.y; Wt[j + 2][o] = v.z; Wt[j + 3][o] = v.w;
        }
    }
#pragma unroll
    for (int r = 0; r < 8; ++r) {
        int f = t + 256 * r;
        float4 v = reinterpret_cast<const float4*>(V)[f];
        if (br != 0) {
#pragma unroll
            for (int k = 1; k < 8; ++k) {
                float4 u = reinterpret_cast<const float4*>(V + 8192 * k)[f];
                v.x += u.x; v.y += u.y; v.z += u.z; v.w += u.w;
            }
        }
        reinterpret_cast<float4*>(vl)[f] = v;
    }
    __syncthreads();

    const int og = t & 7;
    const int bg = t >> 3;
    const int o0 = og * 8;
    const int b0 = bg * 4;

    float acc[4][8];
#pragma unroll
    for (int bb = 0; bb < 4; ++bb)
#pragma unroll
        for (int oo = 0; oo < 8; ++oo) acc[bb][oo] = 0.f;

#pragma unroll 4
    for (int j = 0; j < 64; ++j) {
        float4 vb = *reinterpret_cast<const float4*>(&vl[j * NB + b0]);
        float4 w0 = *reinterpret_cast<const float4*>(&Wt[j][o0]);
        float4 w1 = *reinterpret_cast<const float4*>(&Wt[j][o0 + 4]);
        float vb_[4] = {vb.x, vb.y, vb.z, vb.w};
        float wv_[8] = {w0.x, w0.y, w0.z, w0.w, w1.x, w1.y, w1.z, w1.w};
#pragma unroll
        for (int bb = 0; bb < 4; ++bb)
#pragma unroll
            for (int oo = 0; oo < 8; ++oo)
                acc[bb][oo] += vb_[bb] * wv_[oo];
    }

#pragma unroll
    for (int bb = 0; bb < 4; ++bb)
#pragma unroll
        for (int oo = 0; oo < 8; ++oo) {
            float sg = 1.f / (1.f + __expf(-acc[bb][oo]));
            outT[((size_t)(b0 + bb) * 64 + (o0 + oo)) * 64 + i] = f2bf(sg);
        }
}

// ---------------------------------------------------------------------------
// Kernel 3: c-sweep MFMA recon. Grid 512 = (b, cq of 16 c), 4 waves, wave w
// owns c_local = w*4+cc. Per c: build B-frags A'[p,k]=fc[k,c]*fh[k,p] (fc via
// LDS broadcast, fh pre-converted f32 in regs), 32 MFMA vs resident fw frags,
// 16 float4 stores -> the c's full 16KB [p][q] plane written in one phase.
// ---------------------------------------------------------------------------
__global__ __launch_bounds__(256) void recon_kernel(const unsigned short* __restrict__ fcT,
                                                    const unsigned short* __restrict__ fhT,
                                                    const unsigned short* __restrict__ fwT,
                                                    float* __restrict__ out)
{
    const int blk = blockIdx.x;
    const int b   = blk >> 2;
    const int cq  = blk & 3;
    const int t   = threadIdx.x;
    const int w   = t >> 6;
    const int l   = t & 63;
    const int lr  = l & 15;
    const int lg4 = l >> 4;

    __shared__ __align__(16) unsigned short fhl[64 * 72];  // [p][k]
    __shared__ __align__(16) unsigned short fwl[64 * 72];  // [q][k]
    __shared__ __align__(16) unsigned short fcl[16 * 72];  // [c_local][k]

    const unsigned short* fhb = fhT + (size_t)b * 4096;
    const unsigned short* fwb = fwT + (size_t)b * 4096;
    const unsigned short* fcb = fcT + (size_t)b * 4096 + cq * 1024;

#pragma unroll
    for (int r = 0; r < 2; ++r) {
        int f = t + 256 * r;
        *reinterpret_cast<int4*>(&fhl[(f >> 3) * 72 + (f & 7) * 8]) =
            reinterpret_cast<const int4*>(fhb)[f];
        *reinterpret_cast<int4*>(&fwl[(f >> 3) * 72 + (f & 7) * 8]) =
            reinterpret_cast<const int4*>(fwb)[f];
    }
    if (t < 128) {
        *reinterpret_cast<int4*>(&fcl[(t >> 3) * 72 + (t & 7) * 8]) =
            reinterpret_cast<const int4*>(fcb)[t];
    }
    __syncthreads();

    // fw fragments (A-operand, rows = q)
    bf16x8 afw[4][2];
#pragma unroll
    for (int qt = 0; qt < 4; ++qt)
#pragma unroll
        for (int kb = 0; kb < 2; ++kb)
            afw[qt][kb] = *reinterpret_cast<const bf16x8*>(
                &fwl[(qt * 16 + lr) * 72 + kb * 32 + lg4 * 8]);

    // fh rows = p, pre-converted to f32
    float hvf[4][2][8];
#pragma unroll
    for (int pt = 0; pt < 4; ++pt)
#pragma unroll
        for (int kb = 0; kb < 2; ++kb) {
            bf16x8 h = *reinterpret_cast<const bf16x8*>(
                &fhl[(pt * 16 + lr) * 72 + kb * 32 + lg4 * 8]);
#pragma unroll
            for (int j = 0; j < 8; ++j) hvf[pt][kb][j] = bf2f(h[j]);
        }

    for (int cc = 0; cc < 4; ++cc) {
        const int cl = w * 4 + cc;     // local c 0..15
        // fc[k, c] broadcast within 16-lane group
        float cvf[16];
#pragma unroll
        for (int kb = 0; kb < 2; ++kb) {
            bf16x8 cf = *reinterpret_cast<const bf16x8*>(
                &fcl[cl * 72 + kb * 32 + lg4 * 8]);
#pragma unroll
            for (int j = 0; j < 8; ++j) cvf[kb * 8 + j] = bf2f(cf[j]);
        }
        // B-operand frags: A'[p=lr][k] = fc[k,c]*fh[k,p]
        bf16x8 bp[4][2];
#pragma unroll
        for (int pt = 0; pt < 4; ++pt)
#pragma unroll
            for (int kb = 0; kb < 2; ++kb) {
                union { unsigned u[4]; bf16x8 v; } bu;
#pragma unroll
                for (int jj = 0; jj < 4; ++jj) {
                    float p0 = cvf[kb * 8 + 2 * jj]     * hvf[pt][kb][2 * jj];
                    float p1 = cvf[kb * 8 + 2 * jj + 1] * hvf[pt][kb][2 * jj + 1];
                    bu.u[jj] = packbf2(p0, p1);
                }
                bp[pt][kb] = bu.v;
            }
        // 32 MFMA + 16 float4 stores: full [p][q] plane for c
        float* oc = out + (((size_t)b * 64 + cq * 16 + cl) * 64) * 64;
#pragma unroll
        for (int pt = 0; pt < 4; ++pt)
#pragma unroll
            for (int qt = 0; qt < 4; ++qt) {
                f32x4 a = {0.f, 0.f, 0.f, 0.f};
                a = __builtin_amdgcn_mfma_f32_16x16x32_bf16(afw[qt][0], bp[pt][0], a, 0, 0, 0);
                a = __builtin_amdgcn_mfma_f32_16x16x32_bf16(afw[qt][1], bp[pt][1], a, 0, 0, 0);
                float4 v; v.x = a[0]; v.y = a[1]; v.z = a[2]; v.w = a[3];
                *reinterpret_cast<float4*>(
                    oc + ((size_t)(pt * 16 + lr) * 64) + qt * 16 + lg4 * 4) = v;
            }
    }
}

// ---------------------------------------------------------------------------
extern "C" void kernel_launch(void* const* d_in, const int* in_sizes, int n_in,
                              void* d_out, int out_size, void* d_ws, size_t ws_size,
                              hipStream_t stream) {
    (void)in_sizes; (void)n_in; (void)out_size; (void)ws_size;
    const float* x  = (const float*)d_in[0];
    const float* Wc = (const float*)d_in[1];
    const float* Wh = (const float*)d_in[2];
    const float* Ww = (const float*)d_in[3];
    float* out = (float*)d_out;

    float* ws      = (float*)d_ws;
    float* cvecT   = ws;                 // 64*128 f32
    float* hv_part = ws + 8192;          // 8*64*128 f32
    float* wv_part = ws + 73728;         // 8*64*128 f32
    unsigned short* fcT = (unsigned short*)(ws + 139264);  // 128*64*64 bf16 each
    unsigned short* fhT = fcT + 524288;
    unsigned short* fwT = fhT + 524288;

    pool_kernel<<<1024, 256, 0, stream>>>(x, cvecT, hv_part, wv_part);
    fvec_kernel<<<192, 256, 0, stream>>>(Wc, Wh, Ww, cvecT, hv_part, wv_part, fcT, fhT, fwT);
    recon_kernel<<<512, 256, 0, stream>>>(fcT, fhT, fwT, out);
}